// Round 3
// baseline (168.494 us; speedup 1.0000x reference)
//
#include <hip/hip_runtime.h>

typedef __bf16 bf16_t;
typedef bf16_t bf16x8 __attribute__((ext_vector_type(8)));
typedef bf16_t bf16x4 __attribute__((ext_vector_type(4)));
typedef float f32x4 __attribute__((ext_vector_type(4)));

#define MFMA __builtin_amdgcn_mfma_f32_16x16x32_bf16
#define SWZ(row, off) ((off) ^ (((row) & 7) << 4))

// ws element offsets (bf16), weights transposed [col][k]
#define OFF_W1AT   0
#define OFF_W2AT   65536
#define OFF_W1BT   131072
#define OFF_SMALLT 262144   // Wb1T 64x256 then Wb2aT 64x256
#define OFF_W2BT   294912
// ws byte offsets for intermediates
#define OFF_W2OUT  622592ul
#define OFF_B1ROW  9011200ul
#define OFF_B2OUT  17399808ul
#define OFF_H1     17661952ul

__device__ __forceinline__ bf16x8 cvt8(float4 a, float4 b) {
  bf16x8 v;
  v[0]=(bf16_t)a.x; v[1]=(bf16_t)a.y; v[2]=(bf16_t)a.z; v[3]=(bf16_t)a.w;
  v[4]=(bf16_t)b.x; v[5]=(bf16_t)b.y; v[6]=(bf16_t)b.z; v[7]=(bf16_t)b.w;
  return v;
}

__global__ __launch_bounds__(256) void cvt_wT(
    const float* __restrict__ W1a, const float* __restrict__ W2a,
    const float* __restrict__ W1b, const float* __restrict__ Wb1,
    const float* __restrict__ Wb2a, const float* __restrict__ W2b,
    bf16_t* __restrict__ ws, float* __restrict__ b2out)
{
  int gid = blockIdx.x * 256 + threadIdx.x;
  if (gid >= 311296) {            // tail blocks zero b2out (65536 f32)
    int i = gid - 311296;
    b2out[i] = 0.f;
    return;
  }
  const float* src; int base, nout;
  if (gid < 65536)       { src = W1a;  base = 0;      nout = 256; }
  else if (gid < 131072) { src = W2a;  base = 65536;  nout = 256; }
  else if (gid < 262144) { src = W1b;  base = 131072; nout = 512; }
  else if (gid < 278528) { src = Wb1;  base = 262144; nout = 64;  }
  else if (gid < 294912) { src = Wb2a; base = 278528; nout = 64;  }
  else                   { src = W2b;  base = 294912; nout = 64;  }
  int local = gid - base, col = local >> 8, k = local & 255;
  ws[gid] = (bf16_t)src[k * nout + col];
}

// ---- K1: W2a->h2->W2b->w2, Wb1->b1row, Wb2a-chain->b2 (atomics) ------------
// 512 thr = 8 waves; 128 rows/block; 4 iters x 32 rows.
__global__ __launch_bounds__(512, 4) void qmix_k1(
    const float* __restrict__ s, const bf16_t* __restrict__ ws,
    const float* __restrict__ b2a, const float* __restrict__ b2b,
    const float* __restrict__ bb1, const float* __restrict__ bb2a,
    const float* __restrict__ Wb2b, const float* __restrict__ bb2b,
    bf16_t* __restrict__ w2out, bf16_t* __restrict__ b1row,
    float* __restrict__ b2out)
{
  __shared__ __align__(16) char ldsV[64 * 512];    // W2bT swizzled, 32 KB
  __shared__ __align__(16) char sT[2][32 * 512];   // 32 KB
  __shared__ __align__(16) char h2T[32 * 512];     // 16 KB
  const int tid = threadIdx.x, wave = tid >> 6, lane = tid & 63;
  const int r16 = lane & 15, g = lane >> 4;
  const int row0 = blockIdx.x * 128;
  const int srow = tid >> 4, sc = tid & 15;

  bf16x8 aW[2][8];                  // W2a col-tiles {wave, wave+8}
  #pragma unroll
  for (int t = 0; t < 2; ++t) {
    int col = (wave + t * 8) * 16 + r16;
    #pragma unroll
    for (int kk = 0; kk < 8; ++kk)
      aW[t][kk] = *(const bf16x8*)(ws + OFF_W2AT + col * 256 + kk * 32 + g * 8);
  }
  {
    const char* src = (const char*)(ws + OFF_W2BT);
    for (int c = tid; c < 2048; c += 512) {
      int col = c >> 5, o = (c & 31) * 16;
      *(float4*)(&ldsV[col * 512 + SWZ(col, o)]) = *(const float4*)(src + c * 16);
    }
  }
  {
    const float* p = s + (size_t)(row0 + srow) * 256 + sc * 16;
    *(bf16x8*)(&sT[0][srow * 512 + SWZ(srow, sc * 32)]) =
        cvt8(((const float4*)p)[0], ((const float4*)p)[1]);
    *(bf16x8*)(&sT[0][srow * 512 + SWZ(srow, sc * 32 + 16)]) =
        cvt8(((const float4*)p)[2], ((const float4*)p)[3]);
  }
  __syncthreads();

  const float bb2b0 = bb2b[0];
  for (int rt = 0; rt < 4; ++rt) {
    const int cur = rt & 1;
    const int rowt = row0 + rt * 32;
    float4 pf0, pf1, pf2, pf3;
    if (rt < 3) {
      const float* p = s + (size_t)(rowt + 32 + srow) * 256 + sc * 16;
      pf0 = ((const float4*)p)[0]; pf1 = ((const float4*)p)[1];
      pf2 = ((const float4*)p)[2]; pf3 = ((const float4*)p)[3];
    }
    f32x4 acc[2][2], accS[2];
    #pragma unroll
    for (int t = 0; t < 2; ++t) { acc[t][0] = (f32x4)0.f; acc[t][1] = (f32x4)0.f; }
    accS[0] = (f32x4)0.f; accS[1] = (f32x4)0.f;

    #pragma unroll
    for (int kk = 0; kk < 8; ++kk) {
      bf16x8 aS = *(const bf16x8*)(ws + OFF_SMALLT + (wave * 16 + r16) * 256 + kk * 32 + g * 8);
      #pragma unroll
      for (int h = 0; h < 2; ++h) {
        int rr = h * 16 + r16;
        bf16x8 sB = *(const bf16x8*)(&sT[cur][rr * 512 + SWZ(rr, kk * 64 + g * 16)]);
        acc[0][h] = MFMA(aW[0][kk], sB, acc[0][h], 0, 0, 0);
        acc[1][h] = MFMA(aW[1][kk], sB, acc[1][h], 0, 0, 0);
        accS[h]   = MFMA(aS,        sB, accS[h],   0, 0, 0);
      }
    }
    // h2 = relu(acc + b2a) -> h2T
    #pragma unroll
    for (int t = 0; t < 2; ++t) {
      float4 b0 = *(const float4*)(b2a + (wave + t * 8) * 16 + 4 * g);
      #pragma unroll
      for (int h = 0; h < 2; ++h) {
        int rr = h * 16 + r16;
        bf16x4 hv;
        hv[0] = (bf16_t)fmaxf(acc[t][h][0] + b0.x, 0.f);
        hv[1] = (bf16_t)fmaxf(acc[t][h][1] + b0.y, 0.f);
        hv[2] = (bf16_t)fmaxf(acc[t][h][2] + b0.z, 0.f);
        hv[3] = (bf16_t)fmaxf(acc[t][h][3] + b0.w, 0.f);
        *(bf16x4*)(&h2T[rr * 512 + SWZ(rr, (wave + t * 8) * 32 + 8 * g)]) = hv;
      }
    }
    // small-GEMM epilogues
    if (wave < 4) {
      float4 bb = *(const float4*)(bb1 + wave * 16 + 4 * g);
      #pragma unroll
      for (int h = 0; h < 2; ++h) {
        bf16x4 o;
        o[0]=(bf16_t)(accS[h][0]+bb.x); o[1]=(bf16_t)(accS[h][1]+bb.y);
        o[2]=(bf16_t)(accS[h][2]+bb.z); o[3]=(bf16_t)(accS[h][3]+bb.w);
        *(bf16x4*)(b1row + (size_t)(rowt + h * 16 + r16) * 64 + wave * 16 + 4 * g) = o;
      }
    } else {
      float4 ba = *(const float4*)(bb2a + (wave - 4) * 16 + 4 * g);
      float4 wv = *(const float4*)(Wb2b + (wave - 4) * 16 + 4 * g);
      #pragma unroll
      for (int h = 0; h < 2; ++h) {
        float part = fmaxf(accS[h][0]+ba.x,0.f)*wv.x + fmaxf(accS[h][1]+ba.y,0.f)*wv.y
                   + fmaxf(accS[h][2]+ba.z,0.f)*wv.z + fmaxf(accS[h][3]+ba.w,0.f)*wv.w;
        part += __shfl_xor(part, 16); part += __shfl_xor(part, 32);
        if (lane < 16) {
          float add = part + (wave == 4 ? bb2b0 : 0.f);
          atomicAdd(&b2out[rowt + h * 16 + r16], add);
        }
      }
    }
    if (rt < 3) {
      *(bf16x8*)(&sT[cur ^ 1][srow * 512 + SWZ(srow, sc * 32)])      = cvt8(pf0, pf1);
      *(bf16x8*)(&sT[cur ^ 1][srow * 512 + SWZ(srow, sc * 32 + 16)]) = cvt8(pf2, pf3);
    }
    __syncthreads();
    // stage 2: w2 = |h2 @ W2b + b2b|, all 8 waves (ct = wave>>1, h = wave&1)
    {
      const int ct = wave >> 1, h = wave & 1, rr = h * 16 + r16;
      const int vc = ct * 16 + r16;
      f32x4 accV = (f32x4)0.f;
      #pragma unroll
      for (int kk = 0; kk < 8; ++kk) {
        bf16x8 hB = *(const bf16x8*)(&h2T[rr * 512 + SWZ(rr, kk * 64 + g * 16)]);
        bf16x8 aV = *(const bf16x8*)(&ldsV[vc * 512 + SWZ(vc, kk * 64 + g * 16)]);
        accV = MFMA(aV, hB, accV, 0, 0, 0);
      }
      float4 bv = *(const float4*)(b2b + ct * 16 + 4 * g);
      bf16x4 o;
      o[0]=(bf16_t)fabsf(accV[0]+bv.x); o[1]=(bf16_t)fabsf(accV[1]+bv.y);
      o[2]=(bf16_t)fabsf(accV[2]+bv.z); o[3]=(bf16_t)fabsf(accV[3]+bv.w);
      *(bf16x4*)(w2out + (size_t)(rowt + h * 16 + r16) * 64 + ct * 16 + 4 * g) = o;
    }
    __syncthreads();
  }
}

// ---- K2a: h1 = relu(s @ W1a + b1a) -> ws (bf16 [N][256]) -------------------
__global__ __launch_bounds__(512, 4) void qmix_k2a(
    const float* __restrict__ s, const bf16_t* __restrict__ ws,
    const float* __restrict__ b1a, bf16_t* __restrict__ h1g)
{
  __shared__ __align__(16) char sT[2][32 * 512];
  const int tid = threadIdx.x, wave = tid >> 6, lane = tid & 63;
  const int r16 = lane & 15, g = lane >> 4;
  const int row0 = blockIdx.x * 128;
  const int srow = tid >> 4, sc = tid & 15;

  bf16x8 aA[2][8];                  // W1a col-tiles {wave, wave+8}
  #pragma unroll
  for (int t = 0; t < 2; ++t) {
    int col = (wave + t * 8) * 16 + r16;
    #pragma unroll
    for (int kk = 0; kk < 8; ++kk)
      aA[t][kk] = *(const bf16x8*)(ws + OFF_W1AT + col * 256 + kk * 32 + g * 8);
  }
  {
    const float* p = s + (size_t)(row0 + srow) * 256 + sc * 16;
    *(bf16x8*)(&sT[0][srow * 512 + SWZ(srow, sc * 32)]) =
        cvt8(((const float4*)p)[0], ((const float4*)p)[1]);
    *(bf16x8*)(&sT[0][srow * 512 + SWZ(srow, sc * 32 + 16)]) =
        cvt8(((const float4*)p)[2], ((const float4*)p)[3]);
  }
  __syncthreads();

  for (int rt = 0; rt < 4; ++rt) {
    const int cur = rt & 1;
    const int rowt = row0 + rt * 32;
    float4 pf0, pf1, pf2, pf3;
    if (rt < 3) {
      const float* p = s + (size_t)(rowt + 32 + srow) * 256 + sc * 16;
      pf0 = ((const float4*)p)[0]; pf1 = ((const float4*)p)[1];
      pf2 = ((const float4*)p)[2]; pf3 = ((const float4*)p)[3];
    }
    f32x4 acc[2][2];
    #pragma unroll
    for (int t = 0; t < 2; ++t) { acc[t][0] = (f32x4)0.f; acc[t][1] = (f32x4)0.f; }
    #pragma unroll
    for (int kk = 0; kk < 8; ++kk) {
      #pragma unroll
      for (int h = 0; h < 2; ++h) {
        int rr = h * 16 + r16;
        bf16x8 sB = *(const bf16x8*)(&sT[cur][rr * 512 + SWZ(rr, kk * 64 + g * 16)]);
        acc[0][h] = MFMA(aA[0][kk], sB, acc[0][h], 0, 0, 0);
        acc[1][h] = MFMA(aA[1][kk], sB, acc[1][h], 0, 0, 0);
      }
    }
    #pragma unroll
    for (int t = 0; t < 2; ++t) {
      float4 b0 = *(const float4*)(b1a + (wave + t * 8) * 16 + 4 * g);
      #pragma unroll
      for (int h = 0; h < 2; ++h) {
        bf16x4 hv;
        hv[0] = (bf16_t)fmaxf(acc[t][h][0] + b0.x, 0.f);
        hv[1] = (bf16_t)fmaxf(acc[t][h][1] + b0.y, 0.f);
        hv[2] = (bf16_t)fmaxf(acc[t][h][2] + b0.z, 0.f);
        hv[3] = (bf16_t)fmaxf(acc[t][h][3] + b0.w, 0.f);
        *(bf16x4*)(h1g + (size_t)(rowt + h * 16 + r16) * 256 + (wave + t * 8) * 16 + 4 * g) = hv;
      }
    }
    if (rt < 3) {
      *(bf16x8*)(&sT[cur ^ 1][srow * 512 + SWZ(srow, sc * 32)])      = cvt8(pf0, pf1);
      *(bf16x8*)(&sT[cur ^ 1][srow * 512 + SWZ(srow, sc * 32 + 16)]) = cvt8(pf2, pf3);
    }
    __syncthreads();
  }
}

// ---- K2b: w1 = |h1 @ W1b + b1b|, fold q, elu, dot w2, + b2 -> out ----------
__global__ __launch_bounds__(512, 4) void qmix_k2b(
    const float* __restrict__ q, const bf16_t* __restrict__ ws,
    const float* __restrict__ b1b, const bf16_t* __restrict__ h1g,
    const bf16_t* __restrict__ w2in, const bf16_t* __restrict__ b1row,
    const float* __restrict__ b2in, float* __restrict__ out)
{
  __shared__ __align__(16) char slab[8 * 8192];   // 64 KB f32 fold buffer
  const int tid = threadIdx.x, wave = tid >> 6, lane = tid & 63;
  const int r16 = lane & 15, g = lane >> 4;
  const int row0 = blockIdx.x * 128;

  bf16x8 aB[2][8];                  // W1b tiles tt=0,1 of agent `wave` (tt=2,3 JIT)
  #pragma unroll
  for (int tt = 0; tt < 2; ++tt) {
    int col = wave * 64 + tt * 16 + r16;
    #pragma unroll
    for (int kk = 0; kk < 8; ++kk)
      aB[tt][kk] = *(const bf16x8*)(ws + OFF_W1BT + col * 256 + kk * 32 + g * 8);
  }

  for (int rt = 0; rt < 4; ++rt) {
    const int rowt = row0 + rt * 32;
    float qa0 = q[(size_t)(rowt + r16) * 8 + wave];
    float qa1 = q[(size_t)(rowt + 16 + r16) * 8 + wave];
    f32x4 a2[4][2];
    #pragma unroll
    for (int tt = 0; tt < 4; ++tt) { a2[tt][0] = (f32x4)0.f; a2[tt][1] = (f32x4)0.f; }

    const bf16_t* hbase0 = h1g + (size_t)(rowt + r16) * 256 + g * 8;
    const bf16_t* hbase1 = h1g + (size_t)(rowt + 16 + r16) * 256 + g * 8;
    bf16x8 nb0 = *(const bf16x8*)(hbase0);
    bf16x8 nb1 = *(const bf16x8*)(hbase1);
    #pragma unroll
    for (int kk = 0; kk < 8; ++kk) {
      bf16x8 hb0 = nb0, hb1 = nb1;
      if (kk < 7) {
        nb0 = *(const bf16x8*)(hbase0 + (kk + 1) * 32);
        nb1 = *(const bf16x8*)(hbase1 + (kk + 1) * 32);
      }
      a2[0][0] = MFMA(aB[0][kk], hb0, a2[0][0], 0, 0, 0);
      a2[0][1] = MFMA(aB[0][kk], hb1, a2[0][1], 0, 0, 0);
      a2[1][0] = MFMA(aB[1][kk], hb0, a2[1][0], 0, 0, 0);
      a2[1][1] = MFMA(aB[1][kk], hb1, a2[1][1], 0, 0, 0);
      bf16x8 w2f = *(const bf16x8*)(ws + OFF_W1BT + (wave * 64 + 32 + r16) * 256 + kk * 32 + g * 8);
      a2[2][0] = MFMA(w2f, hb0, a2[2][0], 0, 0, 0);
      a2[2][1] = MFMA(w2f, hb1, a2[2][1], 0, 0, 0);
      bf16x8 w3f = *(const bf16x8*)(ws + OFF_W1BT + (wave * 64 + 48 + r16) * 256 + kk * 32 + g * 8);
      a2[3][0] = MFMA(w3f, hb0, a2[3][0], 0, 0, 0);
      a2[3][1] = MFMA(w3f, hb1, a2[3][1], 0, 0, 0);
    }
    #pragma unroll
    for (int tt = 0; tt < 4; ++tt) {
      float4 bb = *(const float4*)(b1b + wave * 64 + tt * 16 + 4 * g);
      #pragma unroll
      for (int h = 0; h < 2; ++h) {
        float qa = h ? qa1 : qa0;
        int rr = h * 16 + r16;
        f32x4 v;
        v[0] = qa * fabsf(a2[tt][h][0] + bb.x);
        v[1] = qa * fabsf(a2[tt][h][1] + bb.y);
        v[2] = qa * fabsf(a2[tt][h][2] + bb.z);
        v[3] = qa * fabsf(a2[tt][h][3] + bb.w);
        *(f32x4*)(&slab[wave * 8192 + rr * 256 + SWZ(rr, (tt * 16 + 4 * g) * 4)]) = v;
      }
    }
    __syncthreads();
    {
      int row = tid >> 4, qi = (tid & 15) * 4;
      f32x4 sum = (f32x4)0.f;
      #pragma unroll
      for (int a = 0; a < 8; ++a)
        sum += *(const f32x4*)(&slab[a * 8192 + row * 256 + SWZ(row, qi * 4)]);
      bf16x4 b1v = *(const bf16x4*)(b1row + (size_t)(rowt + row) * 64 + qi);
      bf16x4 w2v = *(const bf16x4*)(w2in + (size_t)(rowt + row) * 64 + qi);
      float dot = 0.f;
      #pragma unroll
      for (int e = 0; e < 4; ++e) {
        float hh = sum[e] + (float)b1v[e];
        hh = hh > 0.f ? hh : (__expf(hh) - 1.f);
        dot += hh * (float)w2v[e];
      }
      dot += __shfl_xor(dot, 1); dot += __shfl_xor(dot, 2);
      dot += __shfl_xor(dot, 4); dot += __shfl_xor(dot, 8);
      if ((tid & 15) == 0) out[rowt + row] = dot + b2in[rowt + row];
    }
    __syncthreads();
  }
}

extern "C" void kernel_launch(void* const* d_in, const int* in_sizes, int n_in,
                              void* d_out, int out_size, void* d_ws, size_t ws_size,
                              hipStream_t stream) {
  const float* q    = (const float*)d_in[0];
  const float* s    = (const float*)d_in[1];
  const float* W1a  = (const float*)d_in[2];
  const float* b1a  = (const float*)d_in[3];
  const float* W1b  = (const float*)d_in[4];
  const float* b1b  = (const float*)d_in[5];
  const float* W2a  = (const float*)d_in[6];
  const float* b2a  = (const float*)d_in[7];
  const float* W2b  = (const float*)d_in[8];
  const float* b2b  = (const float*)d_in[9];
  const float* Wb1  = (const float*)d_in[10];
  const float* bb1  = (const float*)d_in[11];
  const float* Wb2a = (const float*)d_in[12];
  const float* bb2a = (const float*)d_in[13];
  const float* Wb2b = (const float*)d_in[14];
  const float* bb2b = (const float*)d_in[15];
  bf16_t* ws = (bf16_t*)d_ws;
  float* out = (float*)d_out;

  bf16_t* w2out = (bf16_t*)((char*)d_ws + OFF_W2OUT);
  bf16_t* b1row = (bf16_t*)((char*)d_ws + OFF_B1ROW);
  float*  b2out = (float*)((char*)d_ws + OFF_B2OUT);
  bf16_t* h1g   = (bf16_t*)((char*)d_ws + OFF_H1);

  int N  = in_sizes[0] / 8;       // 65536 rows
  int nb = N / 128;               // 512 blocks

  cvt_wT<<<1472, 256, 0, stream>>>(W1a, W2a, W1b, Wb1, Wb2a, W2b, ws, b2out);
  qmix_k1<<<nb, 512, 0, stream>>>(s, ws, b2a, b2b, bb1, bb2a, Wb2b, bb2b,
                                  w2out, b1row, b2out);
  qmix_k2a<<<nb, 512, 0, stream>>>(s, ws, b1a, h1g);
  qmix_k2b<<<nb, 512, 0, stream>>>(q, ws, b1b, h1g, w2out, b1row, b2out, out);
}